// Round 1
// baseline (3807.749 us; speedup 1.0000x reference)
//
#include <hip/hip_runtime.h>
#include <math.h>

#define L_NUM 4
#define K_CB  2048
#define D_DIM 256
#define N_ROWS 32768
#define MTI 64
#define RS_STR 260     // padded row stride (floats) for residual tile
#define RED_STR 17     // padded stride for reduction arrays

// ---------- prep 1: per-codeword denominator (max(norm,eps)) + ||cbn||^2 ----------
__global__ __launch_bounds__(64)
void prep_norm_kernel(const float* __restrict__ cb,
                      float* __restrict__ den_out,
                      float* __restrict__ cn2_out) {
  const int b = blockIdx.x;            // l*K + k
  const int lane = threadIdx.x;        // 0..63
  const float4 v = reinterpret_cast<const float4*>(cb + (size_t)b * D_DIM)[lane];
  float s = v.x*v.x + v.y*v.y + v.z*v.z + v.w*v.w;
  #pragma unroll
  for (int m = 1; m < 64; m <<= 1) s += __shfl_xor(s, m, 64);
  const float den = fmaxf(sqrtf(s), 1e-12f);
  // cn2 must be computed from the fp32-rounded normalized values (true divides)
  const float qx = v.x/den, qy = v.y/den, qz = v.z/den, qw = v.w/den;
  float t = qx*qx + qy*qy + qz*qz + qw*qw;
  #pragma unroll
  for (int m = 1; m < 64; m <<= 1) t += __shfl_xor(t, m, 64);
  if (lane == 0) { den_out[b] = den; cn2_out[b] = t; }
}

// ---------- prep 2: write cbn (row-major) and cbnT (transposed [l][d][k]) ----------
__global__ __launch_bounds__(256)
void prep_write_kernel(const float* __restrict__ cb,
                       const float* __restrict__ den,
                       float* __restrict__ cbn,
                       float* __restrict__ cbnT) {
  __shared__ float Ls[64 * 65];        // [d 0..63][k 0..63], stride 65 kills bank conflicts
  const int b = blockIdx.x;            // l(4) * kblk(32) * dblk(4) = 512
  const int dblk = b & 3, kblk = (b >> 2) & 31, l = b >> 7;
  const int k0 = kblk * 64, d0 = dblk * 64;
  const int tid = threadIdx.x;
  #pragma unroll
  for (int i = 0; i < 4; ++i) {
    const int f = tid + i * 256;       // float4 units, 1024 total (64k x 16 d4)
    const int kk = f >> 4, d4 = f & 15;
    const size_t src = ((size_t)(l * K_CB + k0 + kk)) * D_DIM + d0 + d4 * 4;
    float4 v = *(const float4*)(cb + src);
    const float dn = den[l * K_CB + k0 + kk];
    v.x /= dn; v.y /= dn; v.z /= dn; v.w /= dn;   // true division to match reference rounding
    *(float4*)(cbn + src) = v;
    Ls[(d4*4+0)*65 + kk] = v.x;
    Ls[(d4*4+1)*65 + kk] = v.y;
    Ls[(d4*4+2)*65 + kk] = v.z;
    Ls[(d4*4+3)*65 + kk] = v.w;
  }
  __syncthreads();
  #pragma unroll
  for (int i = 0; i < 4; ++i) {
    const int f = tid + i * 256;
    const int dd = f >> 4, k4 = f & 15;
    float4 v;
    v.x = Ls[dd*65 + k4*4+0];
    v.y = Ls[dd*65 + k4*4+1];
    v.z = Ls[dd*65 + k4*4+2];
    v.w = Ls[dd*65 + k4*4+3];
    *(float4*)(cbnT + ((size_t)(l * D_DIM + d0 + dd)) * K_CB + k0 + k4*4) = v;
  }
}

// ---------- fused main: 64 rows/block, residual resident in LDS across 4 layers ----------
__global__ __launch_bounds__(256, 1)
void rq_main_kernel(const float* __restrict__ x,
                    const float* __restrict__ cb,
                    const float* __restrict__ cbn,
                    const float* __restrict__ cbnT,
                    const float* __restrict__ cn2,
                    float* __restrict__ out_ids,
                    float* __restrict__ out_dec,
                    double* __restrict__ dloss) {
  extern __shared__ char smem_raw[];
  float* Rs   = (float*)smem_raw;                  // [64][RS_STR]
  float* Cst  = Rs + 64 * RS_STR;                  // [256][64]  transposed codebook tile
  float* rr_s = Cst + 256 * 64;                    // [64]
  float* redv = rr_s + 64;                         // [2][64][RED_STR]
  int*   redi = (int*)(redv + 2 * 64 * RED_STR);   // [2][64][RED_STR]
  int*   idx1_s = redi + 2 * 64 * RED_STR;         // [64]
  int*   idx2_s = idx1_s + 64;                     // [64]

  const int tid = threadIdx.x;
  const int ty = tid >> 4, tx = tid & 15;
  const int row0 = blockIdx.x * MTI;
  const int urow = tid >> 2, uo = (tid & 3) << 6;  // update mapping: 4 threads/row, 64 dims each

  {
    const float4* xg = (const float4*)(x + (size_t)row0 * D_DIM);
    #pragma unroll
    for (int i = 0; i < 16; ++i) {
      const int f = tid + i * 256;
      const int m = f >> 6, d4 = f & 63;
      *(float4*)(Rs + m * RS_STR + d4 * 4) = xg[f];
    }
  }
  float dec[64];
  #pragma unroll
  for (int i = 0; i < 64; ++i) dec[i] = 0.f;
  double lloss = 0.0;
  __syncthreads();

  for (int l = 0; l < L_NUM; ++l) {
    // per-row squared norm (fp32, matches reference formula term)
    {
      const float* rp = Rs + urow * RS_STR + uo;
      float p = 0.f;
      #pragma unroll
      for (int d = 0; d < 64; ++d) p = fmaf(rp[d], rp[d], p);
      p += __shfl_xor(p, 1, 64);
      p += __shfl_xor(p, 2, 64);
      if ((tid & 3) == 0) rr_s[urow] = p;
    }
    __syncthreads();

    float bv1[4], bv2[4]; int bi1[4], bi2[4];
    #pragma unroll
    for (int m = 0; m < 4; ++m) { bv1[m] = bv2[m] = INFINITY; bi1[m] = bi2[m] = 0x7fffffff; }

    const float* cT = cbnT + (size_t)l * D_DIM * K_CB;
    const float* c2 = cn2 + l * K_CB;

    for (int kt = 0; kt < K_CB / 64; ++kt) {
      // stage transposed codebook tile [256 d][64 k]
      #pragma unroll
      for (int i = 0; i < 16; ++i) {
        const int f = tid + i * 256;     // float4 units, 4096 total
        const int d = f >> 4, k4 = f & 15;
        *(float4*)(Cst + d * 64 + k4 * 4) =
            *(const float4*)(cT + (size_t)d * K_CB + kt * 64 + k4 * 4);
      }
      __syncthreads();

      float acc[4][4];
      #pragma unroll
      for (int m = 0; m < 4; ++m)
        #pragma unroll
        for (int k = 0; k < 4; ++k) acc[m][k] = 0.f;

      const float* rbase = Rs + (ty * 4) * RS_STR;
      const float* cbase = Cst + tx * 4;
      #pragma unroll 2
      for (int d4 = 0; d4 < 64; ++d4) {
        float a[4][4], b[4][4];
        #pragma unroll
        for (int m = 0; m < 4; ++m) {
          const float4 av = *(const float4*)(rbase + m * RS_STR + d4 * 4);
          a[m][0]=av.x; a[m][1]=av.y; a[m][2]=av.z; a[m][3]=av.w;
        }
        #pragma unroll
        for (int j = 0; j < 4; ++j) {
          const float4 bv = *(const float4*)(cbase + (d4 * 4 + j) * 64);
          b[j][0]=bv.x; b[j][1]=bv.y; b[j][2]=bv.z; b[j][3]=bv.w;
        }
        #pragma unroll
        for (int m = 0; m < 4; ++m)
          #pragma unroll
          for (int j = 0; j < 4; ++j) {
            acc[m][0] = fmaf(a[m][j], b[j][0], acc[m][0]);
            acc[m][1] = fmaf(a[m][j], b[j][1], acc[m][1]);
            acc[m][2] = fmaf(a[m][j], b[j][2], acc[m][2]);
            acc[m][3] = fmaf(a[m][j], b[j][3], acc[m][3]);
          }
      }

      // top-2 (value, index) per row over this thread's k's (ascending scan)
      #pragma unroll
      for (int m = 0; m < 4; ++m) {
        const float rrm = rr_s[ty * 4 + m];
        #pragma unroll
        for (int k = 0; k < 4; ++k) {
          const int kg = kt * 64 + tx * 4 + k;
          const float d2 = (rrm - 2.f * acc[m][k]) + c2[kg];
          if (d2 < bv1[m]) { bv2[m]=bv1[m]; bi2[m]=bi1[m]; bv1[m]=d2; bi1[m]=kg; }
          else if (d2 < bv2[m]) { bv2[m]=d2; bi2[m]=kg; }
        }
      }
      __syncthreads();
    }

    // write per-thread top-2, merge across the 16 k-threads per row
    #pragma unroll
    for (int m = 0; m < 4; ++m) {
      const int r = ty * 4 + m;
      redv[(0 * 64 + r) * RED_STR + tx] = bv1[m];
      redi[(0 * 64 + r) * RED_STR + tx] = bi1[m];
      redv[(1 * 64 + r) * RED_STR + tx] = bv2[m];
      redi[(1 * 64 + r) * RED_STR + tx] = bi2[m];
    }
    __syncthreads();

    if (tid < 64) {
      const int r = tid;
      float v1 = INFINITY, v2 = INFINITY; int i1 = 0x7fffffff, i2 = 0x7fffffff;
      for (int s = 0; s < 2; ++s)
        for (int t = 0; t < 16; ++t) {
          const float v = redv[(s * 64 + r) * RED_STR + t];
          const int   i = redi[(s * 64 + r) * RED_STR + t];
          if (v < v1 || (v == v1 && i < i1)) { v2 = v1; i2 = i1; v1 = v; i1 = i; }
          else if (v < v2 || (v == v2 && i < i2)) { v2 = v; i2 = i; }
        }
      idx1_s[r] = i1; idx2_s[r] = i2;
    }
    __syncthreads();

    // exact double-precision re-rank of the top-2 candidates (kills fp32 near-tie flips)
    {
      const int r = urow;
      const int c1i = idx1_s[r], c2i = idx2_s[r];
      const float* rp = Rs + r * RS_STR + uo;
      const float* p1 = cbn + ((size_t)l * K_CB + c1i) * D_DIM + uo;
      const float* p2 = cbn + ((size_t)l * K_CB + c2i) * D_DIM + uo;
      double s1 = 0.0, s2 = 0.0;
      #pragma unroll 4
      for (int d = 0; d < 64; d += 4) {
        const float4 rv = *(const float4*)(rp + d);
        const float4 u1 = *(const float4*)(p1 + d);
        const float4 u2 = *(const float4*)(p2 + d);
        s1 = fma((double)rv.x, (double)u1.x, s1);
        s1 = fma((double)rv.y, (double)u1.y, s1);
        s1 = fma((double)rv.z, (double)u1.z, s1);
        s1 = fma((double)rv.w, (double)u1.w, s1);
        s2 = fma((double)rv.x, (double)u2.x, s2);
        s2 = fma((double)rv.y, (double)u2.y, s2);
        s2 = fma((double)rv.z, (double)u2.z, s2);
        s2 = fma((double)rv.w, (double)u2.w, s2);
      }
      s1 += __shfl_xor(s1, 1, 64); s1 += __shfl_xor(s1, 2, 64);
      s2 += __shfl_xor(s2, 1, 64); s2 += __shfl_xor(s2, 2, 64);
      if ((tid & 3) == 0) {
        const double da = -2.0 * s1 + (double)c2[c1i];   // rr term is constant per row
        const double db = -2.0 * s2 + (double)c2[c2i];
        int fin = c1i;
        if (db < da || (db == da && c2i < c1i)) fin = c2i;
        idx1_s[r] = fin;
        out_ids[(size_t)(row0 + r) * L_NUM + l] = (float)fin;
      }
    }
    __syncthreads();

    // update: gather RAW codeword, residual -= q, decoded += q, loss += ||r_new||^2
    {
      const int r = urow;
      const float* qg = cb + ((size_t)l * K_CB + idx1_s[r]) * D_DIM + uo;
      float* rp = Rs + r * RS_STR + uo;
      #pragma unroll
      for (int i = 0; i < 16; ++i) {
        const float4 q = *(const float4*)(qg + i * 4);
        float4 rv = *(float4*)(rp + i * 4);
        rv.x -= q.x; rv.y -= q.y; rv.z -= q.z; rv.w -= q.w;
        *(float4*)(rp + i * 4) = rv;
        dec[i*4+0] += q.x; dec[i*4+1] += q.y; dec[i*4+2] += q.z; dec[i*4+3] += q.w;
        lloss += (double)rv.x * rv.x + (double)rv.y * rv.y
               + (double)rv.z * rv.z + (double)rv.w * rv.w;
      }
    }
    __syncthreads();
  }

  // decoded out
  {
    float* og = out_dec + (size_t)(row0 + urow) * D_DIM + uo;
    #pragma unroll
    for (int i = 0; i < 16; ++i) {
      float4 v;
      v.x = dec[i*4+0]; v.y = dec[i*4+1]; v.z = dec[i*4+2]; v.w = dec[i*4+3];
      *(float4*)(og + i * 4) = v;
    }
  }
  // block loss reduction -> one double atomic
  #pragma unroll
  for (int m = 1; m < 64; m <<= 1) lloss += __shfl_xor(lloss, m, 64);
  double* dred = (double*)rr_s;   // rr_s dead by now; 8B-aligned
  if ((tid & 63) == 0) dred[tid >> 6] = lloss;
  __syncthreads();
  if (tid == 0) atomicAdd(dloss, dred[0] + dred[1] + dred[2] + dred[3]);
}

__global__ void rq_fin_kernel(const double* __restrict__ dls, float* __restrict__ out_loss) {
  // loss = sum_l (1 + BETA) * ||r-q||^2 / n_elem   (codebook and commitment terms are equal)
  out_loss[0] = (float)(dls[0] * 1.25 / 8388608.0);
}

extern "C" void kernel_launch(void* const* d_in, const int* in_sizes, int n_in,
                              void* d_out, int out_size, void* d_ws, size_t ws_size,
                              hipStream_t stream) {
  const float* x  = (const float*)d_in[0];
  const float* cb = (const float*)d_in[1];
  float* out      = (float*)d_out;
  float* out_ids  = out;                                          // [N][4] as float
  float* out_dec  = out + (size_t)N_ROWS * L_NUM;                 // [N][256]
  float* out_loss = out + (size_t)N_ROWS * L_NUM + (size_t)N_ROWS * D_DIM;

  float* den  = (float*)d_ws;                                     // [4][2048]
  float* cn2  = den + L_NUM * K_CB;                               // [4][2048]
  float* cbn  = cn2 + L_NUM * K_CB;                               // [4][2048][256]
  float* cbnT = cbn + (size_t)L_NUM * K_CB * D_DIM;               // [4][256][2048]
  double* dls = (double*)(cbnT + (size_t)L_NUM * K_CB * D_DIM);   // 1 double

  hipMemsetAsync(dls, 0, sizeof(double), stream);
  prep_norm_kernel<<<L_NUM * K_CB, 64, 0, stream>>>(cb, den, cn2);
  prep_write_kernel<<<512, 256, 0, stream>>>(cb, den, cbn, cbnT);

  const size_t smem = (size_t)(64 * RS_STR + 256 * 64 + 64 + 2 * 64 * RED_STR) * 4
                    + (size_t)(2 * 64 * RED_STR + 64 + 64) * 4;   // 150272 B
  hipFuncSetAttribute(reinterpret_cast<const void*>(rq_main_kernel),
                      hipFuncAttributeMaxDynamicSharedMemorySize, (int)smem);
  rq_main_kernel<<<N_ROWS / MTI, 256, smem, stream>>>(x, cb, cbn, cbnT, cn2,
                                                      out_ids, out_dec, dls);
  rq_fin_kernel<<<1, 1, 0, stream>>>(dls, out_loss);
}

// Round 2
// 803.332 us; speedup vs baseline: 4.7399x; 4.7399x over previous
//
#include <hip/hip_runtime.h>
#include <math.h>

#define L_NUM 4
#define K_CB  2048
#define D_DIM 256
#define N_ROWS 32768

typedef _Float16 half8 __attribute__((ext_vector_type(8)));
typedef _Float16 half4v __attribute__((ext_vector_type(4)));
typedef float f32x4 __attribute__((ext_vector_type(4)));

// ---------- prep 1: per-codeword denominator (max(norm,eps)) + ||cbn||^2 ----------
__global__ __launch_bounds__(64)
void prep_norm_kernel(const float* __restrict__ cb,
                      float* __restrict__ den_out,
                      float* __restrict__ cn2_out) {
  const int b = blockIdx.x;            // l*K + k
  const int lane = threadIdx.x;        // 0..63
  const float4 v = reinterpret_cast<const float4*>(cb + (size_t)b * D_DIM)[lane];
  float s = v.x*v.x + v.y*v.y + v.z*v.z + v.w*v.w;
  #pragma unroll
  for (int m = 1; m < 64; m <<= 1) s += __shfl_xor(s, m, 64);
  const float den = fmaxf(sqrtf(s), 1e-12f);
  const float qx = v.x/den, qy = v.y/den, qz = v.z/den, qw = v.w/den;
  float t = qx*qx + qy*qy + qz*qz + qw*qw;
  #pragma unroll
  for (int m = 1; m < 64; m <<= 1) t += __shfl_xor(t, m, 64);
  if (lane == 0) { den_out[b] = den; cn2_out[b] = t; }
}

// ---------- prep 2: write cbn fp32 and cb16 fp16 (both row-major [k][256]) ----------
__global__ __launch_bounds__(64)
void prep_write2_kernel(const float* __restrict__ cb,
                        const float* __restrict__ den,
                        float* __restrict__ cbn,
                        _Float16* __restrict__ cb16) {
  const int b = blockIdx.x;
  const int lane = threadIdx.x;
  const float dn = den[b];
  float4 v = reinterpret_cast<const float4*>(cb + (size_t)b * D_DIM)[lane];
  v.x /= dn; v.y /= dn; v.z /= dn; v.w /= dn;     // true division = reference rounding
  reinterpret_cast<float4*>(cbn + (size_t)b * D_DIM)[lane] = v;
  half4v h;
  h[0] = (_Float16)v.x; h[1] = (_Float16)v.y; h[2] = (_Float16)v.z; h[3] = (_Float16)v.w;
  reinterpret_cast<half4v*>(cb16 + (size_t)b * D_DIM)[lane] = h;
}

// ---------- layer-0 residual fp16 ----------
__global__ __launch_bounds__(256)
void init16_kernel(const float* __restrict__ x, _Float16* __restrict__ R16) {
  const int i = blockIdx.x * 256 + threadIdx.x;   // 8 floats each
  const float4 a = ((const float4*)x)[(size_t)i*2+0];
  const float4 b = ((const float4*)x)[(size_t)i*2+1];
  half8 h;
  h[0]=(_Float16)a.x; h[1]=(_Float16)a.y; h[2]=(_Float16)a.z; h[3]=(_Float16)a.w;
  h[4]=(_Float16)b.x; h[5]=(_Float16)b.y; h[6]=(_Float16)b.z; h[7]=(_Float16)b.w;
  ((half8*)R16)[i] = h;
}

#define INS4(s, c) do { \
  const float _s = (s); const int _c = (c); \
  if (_s < v3) { \
    if (_s < v1) { \
      if (_s < v0) { v3=v2;i3=i2; v2=v1;i2=i1; v1=v0;i1=i0; v0=_s;i0=_c; } \
      else          { v3=v2;i3=i2; v2=v1;i2=i1; v1=_s;i1=_c; } \
    } else { \
      if (_s < v2) { v3=v2;i3=i2; v2=_s;i2=_c; } \
      else          { v3=_s;i3=_c; } \
    } \
  } } while(0)

// ---------- per-layer: fp16 MFMA score GEMM + per-row/tile top-4 ----------
__global__ __launch_bounds__(256, 2)
void gemm_topk_kernel(const _Float16* __restrict__ A16,
                      const _Float16* __restrict__ B16,   // layer codebook fp16
                      const float* __restrict__ c2l,      // layer ||cbn||^2
                      float* __restrict__ cand_v,
                      int* __restrict__ cand_i) {
  extern __shared__ char sm[];
  _Float16* As = (_Float16*)sm;                       // [128][72] fp16
  _Float16* Bs = As + 128*72;                         // [128][72] fp16
  float* Sc = (float*)sm;                             // [128][132] f32 (overlays As/Bs)
  float* mv = (float*)(sm + 128*132*4);               // [128][2][4]
  int*   mi = (int*)(sm + 128*132*4 + 128*8*4);       // [128][2][4]

  const int tid = threadIdx.x;
  const int mt = blockIdx.x & 255, nt = blockIdx.x >> 8;
  const int ln = tid & 63, wid = tid >> 6;
  const int wm = wid >> 1, wn = wid & 1;

  f32x4 acc[4][4];
  #pragma unroll
  for (int i = 0; i < 4; ++i)
    #pragma unroll
    for (int j = 0; j < 4; ++j)
      #pragma unroll
      for (int e = 0; e < 4; ++e) acc[i][j][e] = 0.f;

  const _Float16* Ag = A16 + (size_t)(mt*128) * D_DIM;
  const _Float16* Bg = B16 + (size_t)(nt*128) * D_DIM;

  #pragma unroll 1
  for (int kt = 0; kt < 4; ++kt) {
    #pragma unroll
    for (int i = 0; i < 4; ++i) {
      const int c = tid + i*256, r = c >> 3, kb = c & 7;
      *(float4*)(As + r*72 + kb*8) = *(const float4*)(Ag + (size_t)r*D_DIM + kt*64 + kb*8);
      *(float4*)(Bs + r*72 + kb*8) = *(const float4*)(Bg + (size_t)r*D_DIM + kt*64 + kb*8);
    }
    __syncthreads();
    #pragma unroll
    for (int ks = 0; ks < 2; ++ks) {
      const int ko = ks*32 + (ln>>4)*8;
      half8 af[4], bf[4];
      #pragma unroll
      for (int f = 0; f < 4; ++f) {
        af[f] = *(const half8*)(As + (wm*64 + f*16 + (ln&15))*72 + ko);
        bf[f] = *(const half8*)(Bs + (wn*64 + f*16 + (ln&15))*72 + ko);
      }
      #pragma unroll
      for (int fm = 0; fm < 4; ++fm)
        #pragma unroll
        for (int fn = 0; fn < 4; ++fn)
          acc[fm][fn] = __builtin_amdgcn_mfma_f32_16x16x32_f16(af[fm], bf[fn], acc[fm][fn], 0, 0, 0);
    }
    __syncthreads();
  }

  // scores -> LDS (reuses tile space; last __syncthreads above retired all reads)
  float c2r[4];
  #pragma unroll
  for (int fn = 0; fn < 4; ++fn) c2r[fn] = c2l[nt*128 + wn*64 + fn*16 + (ln&15)];
  #pragma unroll
  for (int fm = 0; fm < 4; ++fm)
    #pragma unroll
    for (int fn = 0; fn < 4; ++fn)
      #pragma unroll
      for (int rg = 0; rg < 4; ++rg) {
        const int row = wm*64 + fm*16 + (ln>>4)*4 + rg;
        const int col = wn*64 + fn*16 + (ln&15);
        Sc[row*132 + col] = fmaf(-2.f, acc[fm][fn][rg], c2r[fn]);
      }
  __syncthreads();

  // per-row top-4 over each 64-col half (strict < keeps earlier index on ties)
  {
    const int row = tid >> 1, h = tid & 1;
    const float4* p4 = (const float4*)(Sc + row*132 + h*64);
    float v0=INFINITY, v1=INFINITY, v2=INFINITY, v3=INFINITY;
    int i0=0, i1=0, i2=0, i3=0;
    const int cb0 = h*64;
    #pragma unroll 1
    for (int i = 0; i < 16; ++i) {
      const float4 s = p4[i];
      INS4(s.x, cb0 + i*4 + 0);
      INS4(s.y, cb0 + i*4 + 1);
      INS4(s.z, cb0 + i*4 + 2);
      INS4(s.w, cb0 + i*4 + 3);
    }
    const int o = (row*2 + h)*4;
    mv[o+0]=v0; mv[o+1]=v1; mv[o+2]=v2; mv[o+3]=v3;
    mi[o+0]=i0; mi[o+1]=i1; mi[o+2]=i2; mi[o+3]=i3;
  }
  __syncthreads();

  // merge two sorted-4 lists -> per-tile top-4, write candidates
  if (tid < 128) {
    const float* Av = mv + (tid*2)*4;
    const float* Bv = Av + 4;
    const int* Ai = mi + (tid*2)*4;
    const int* Bi = Ai + 4;
    float* ov = cand_v + ((size_t)(mt*128 + tid))*64 + nt*4;
    int*   oi = cand_i + ((size_t)(mt*128 + tid))*64 + nt*4;
    int pa = 0, pb = 0;
    #pragma unroll
    for (int j = 0; j < 4; ++j) {
      const float va = Av[pa], vb = Bv[pb];
      const bool ta = (va <= vb);           // tie -> lower col (h=0 first)
      ov[j] = ta ? va : vb;
      oi[j] = (ta ? Ai[pa] : Bi[pb]) + nt*128;
      pa += ta ? 1 : 0; pb += ta ? 0 : 1;
    }
  }
}

// ---------- per-layer: merge candidates, exact double re-rank, update ----------
__global__ __launch_bounds__(256)
void merge_update_kernel(const int l,
                         const float* __restrict__ x,
                         const float* __restrict__ cb,
                         const float* __restrict__ cbn,
                         const float* __restrict__ c2,      // full [4][2048]
                         const float* __restrict__ cand_v,
                         const int* __restrict__ cand_i,
                         float* __restrict__ out_ids,
                         float* __restrict__ out_dec,
                         _Float16* __restrict__ R16,
                         double* __restrict__ dloss) {
  __shared__ int idx8[64][8];
  __shared__ double lw[4];
  const int tid = threadIdx.x;
  const int row0 = blockIdx.x * 64;

  // phase 1: per-row top-8 of the 64 (16 tiles x 4) candidates by approx score
  if (tid < 64) {
    const int row = row0 + tid;
    float v[8]; int ix[8];
    #pragma unroll
    for (int j = 0; j < 8; ++j) { v[j] = INFINITY; ix[j] = 0; }
    auto ins8 = [&](float s, int c) {
      if (s < v[7]) {
        #pragma unroll
        for (int p = 7; p >= 1; --p) {
          const bool shift = (s < v[p-1]);
          const bool place = !shift && (s < v[p]);
          const float nv = shift ? v[p-1] : (place ? s : v[p]);
          const int   ni = shift ? ix[p-1] : (place ? c : ix[p]);
          v[p] = nv; ix[p] = ni;
        }
        if (s < v[0]) { v[0] = s; ix[0] = c; }
      }
    };
    const float4* cv = (const float4*)(cand_v + (size_t)row*64);
    const int4*   ci = (const int4*)(cand_i + (size_t)row*64);
    #pragma unroll 1
    for (int t = 0; t < 16; ++t) {
      const float4 s = cv[t]; const int4 id = ci[t];
      ins8(s.x, id.x); ins8(s.y, id.y); ins8(s.z, id.z); ins8(s.w, id.w);
    }
    #pragma unroll
    for (int j = 0; j < 8; ++j) idx8[tid][j] = ix[j];
  }
  __syncthreads();

  // phase 2: recompute fp32 residual exactly (sequential subtraction = ref rounding)
  const int rt = tid >> 2, qo = (tid & 3) * 64;
  const int row = row0 + rt;
  float r[64];
  {
    const float4* xg = (const float4*)(x + (size_t)row*D_DIM + qo);
    #pragma unroll
    for (int i = 0; i < 16; ++i) {
      const float4 a = xg[i];
      r[i*4+0]=a.x; r[i*4+1]=a.y; r[i*4+2]=a.z; r[i*4+3]=a.w;
    }
  }
  #pragma unroll 1
  for (int j = 0; j < l; ++j) {
    const int pj = (int)out_ids[(size_t)row*L_NUM + j];
    const float4* qg = (const float4*)(cb + ((size_t)j*K_CB + pj)*D_DIM + qo);
    #pragma unroll
    for (int i = 0; i < 16; ++i) {
      const float4 a = qg[i];
      r[i*4+0]-=a.x; r[i*4+1]-=a.y; r[i*4+2]-=a.z; r[i*4+3]-=a.w;
    }
  }

  // phase 3: exact double re-rank of the 8 candidates
  double bs = (double)INFINITY; int bi = 0x7fffffff;
  #pragma unroll 1
  for (int c = 0; c < 8; ++c) {
    const int cidx = idx8[rt][c];
    const float4* cp = (const float4*)(cbn + ((size_t)l*K_CB + cidx)*D_DIM + qo);
    double s = 0.0;
    #pragma unroll
    for (int i = 0; i < 16; ++i) {
      const float4 a = cp[i];
      s = fma((double)r[i*4+0], (double)a.x, s);
      s = fma((double)r[i*4+1], (double)a.y, s);
      s = fma((double)r[i*4+2], (double)a.z, s);
      s = fma((double)r[i*4+3], (double)a.w, s);
    }
    s += __shfl_xor(s, 1, 64);
    s += __shfl_xor(s, 2, 64);
    const double sc = -2.0 * s + (double)c2[l*K_CB + cidx];
    if (sc < bs || (sc == bs && cidx < bi)) { bs = sc; bi = cidx; }
  }
  if ((tid & 3) == 0) out_ids[(size_t)row*L_NUM + l] = (float)bi;

  // phase 4: gather RAW codeword; decoded += q; r_new = r - q; loss; R16 for next layer
  double lloss = 0.0;
  {
    const float4* qg = (const float4*)(cb + ((size_t)l*K_CB + bi)*D_DIM + qo);
    float4* dg = (float4*)(out_dec + (size_t)row*D_DIM + qo);
    _Float16* rg = R16 + (size_t)row*D_DIM + qo;
    #pragma unroll
    for (int i = 0; i < 8; ++i) {     // 8 dims per iter
      const float4 q0 = qg[i*2+0], q1 = qg[i*2+1];
      float rn[8];
      rn[0]=r[i*8+0]-q0.x; rn[1]=r[i*8+1]-q0.y; rn[2]=r[i*8+2]-q0.z; rn[3]=r[i*8+3]-q0.w;
      rn[4]=r[i*8+4]-q1.x; rn[5]=r[i*8+5]-q1.y; rn[6]=r[i*8+6]-q1.z; rn[7]=r[i*8+7]-q1.w;
      float4 d0, d1;
      if (l == 0) { d0 = q0; d1 = q1; }
      else {
        d0 = dg[i*2+0]; d0.x+=q0.x; d0.y+=q0.y; d0.z+=q0.z; d0.w+=q0.w;
        d1 = dg[i*2+1]; d1.x+=q1.x; d1.y+=q1.y; d1.z+=q1.z; d1.w+=q1.w;
      }
      dg[i*2+0] = d0; dg[i*2+1] = d1;
      lloss += (double)rn[0]*rn[0] + (double)rn[1]*rn[1]
             + (double)rn[2]*rn[2] + (double)rn[3]*rn[3]
             + (double)rn[4]*rn[4] + (double)rn[5]*rn[5]
             + (double)rn[6]*rn[6] + (double)rn[7]*rn[7];
      if (l < 3) {
        half8 h;
        h[0]=(_Float16)rn[0]; h[1]=(_Float16)rn[1]; h[2]=(_Float16)rn[2]; h[3]=(_Float16)rn[3];
        h[4]=(_Float16)rn[4]; h[5]=(_Float16)rn[5]; h[6]=(_Float16)rn[6]; h[7]=(_Float16)rn[7];
        *(half8*)(rg + i*8) = h;
      }
    }
  }
  #pragma unroll
  for (int m = 1; m < 64; m <<= 1) lloss += __shfl_xor(lloss, m, 64);
  if ((tid & 63) == 0) lw[tid >> 6] = lloss;
  __syncthreads();
  if (tid == 0) atomicAdd(dloss, lw[0]+lw[1]+lw[2]+lw[3]);
}

__global__ void rq_fin_kernel(const double* __restrict__ dls, float* __restrict__ out_loss) {
  // loss = sum_l (1 + BETA) * ||r-q||^2 / n_elem  (codebook and commitment terms equal)
  out_loss[0] = (float)(dls[0] * 1.25 / 8388608.0);
}

extern "C" void kernel_launch(void* const* d_in, const int* in_sizes, int n_in,
                              void* d_out, int out_size, void* d_ws, size_t ws_size,
                              hipStream_t stream) {
  const float* x  = (const float*)d_in[0];
  const float* cb = (const float*)d_in[1];
  float* out      = (float*)d_out;
  float* out_ids  = out;                                   // [N][4] as float
  float* out_dec  = out + (size_t)N_ROWS * L_NUM;          // [N][256]
  float* out_loss = out_dec + (size_t)N_ROWS * D_DIM;

  char* w = (char*)d_ws;
  float* den = (float*)w;                     w += (size_t)L_NUM*K_CB*4;
  float* c2  = (float*)w;                     w += (size_t)L_NUM*K_CB*4;
  double* dls = (double*)w;                   w += 256;
  float* cbn = (float*)w;                     w += (size_t)L_NUM*K_CB*D_DIM*4;
  _Float16* cb16 = (_Float16*)w;              w += (size_t)L_NUM*K_CB*D_DIM*2;
  _Float16* R16 = (_Float16*)w;               w += (size_t)N_ROWS*D_DIM*2;
  float* cand_v = (float*)w;                  w += (size_t)N_ROWS*64*4;
  int* cand_i = (int*)w;                      w += (size_t)N_ROWS*64*4;

  hipMemsetAsync(dls, 0, sizeof(double), stream);
  prep_norm_kernel<<<L_NUM*K_CB, 64, 0, stream>>>(cb, den, c2);
  prep_write2_kernel<<<L_NUM*K_CB, 64, 0, stream>>>(cb, den, cbn, cb16);
  init16_kernel<<<(N_ROWS*D_DIM/8 + 255)/256, 256, 0, stream>>>(x, R16);

  const size_t smem = 128*132*4 + 128*8*4 + 128*8*4;   // 75776 B
  hipFuncSetAttribute(reinterpret_cast<const void*>(gemm_topk_kernel),
                      hipFuncAttributeMaxDynamicSharedMemorySize, (int)smem);

  for (int l = 0; l < L_NUM; ++l) {
    gemm_topk_kernel<<<4096, 256, smem, stream>>>(
        R16, cb16 + (size_t)l*K_CB*D_DIM, c2 + l*K_CB, cand_v, cand_i);
    merge_update_kernel<<<N_ROWS/64, 256, 0, stream>>>(
        l, x, cb, cbn, c2, cand_v, cand_i, out_ids, out_dec, R16, dls);
  }
  rq_fin_kernel<<<1, 1, 0, stream>>>(dls, out_loss);
}

// Round 3
// 700.303 us; speedup vs baseline: 5.4373x; 1.1471x over previous
//
#include <hip/hip_runtime.h>
#include <math.h>

#define L_NUM 4
#define K_CB  2048
#define D_DIM 256
#define N_ROWS 32768
#define CAP   48          // candidate slots per row
#define DELTA  0.125f     // collect threshold (worst-case fp16 score err*2 = ~0.10)
#define DELTA2 0.15f      // merge filter threshold (> DELTA)

typedef _Float16 half8 __attribute__((ext_vector_type(8)));
typedef _Float16 half4v __attribute__((ext_vector_type(4)));
typedef float f32x4 __attribute__((ext_vector_type(4)));

// ---------- prep 1: per-codeword denominator (max(norm,eps)) + ||cbn||^2 ----------
__global__ __launch_bounds__(64)
void prep_norm_kernel(const float* __restrict__ cb,
                      float* __restrict__ den_out,
                      float* __restrict__ cn2_out) {
  const int b = blockIdx.x;            // l*K + k
  const int lane = threadIdx.x;        // 0..63
  const float4 v = reinterpret_cast<const float4*>(cb + (size_t)b * D_DIM)[lane];
  float s = v.x*v.x + v.y*v.y + v.z*v.z + v.w*v.w;
  #pragma unroll
  for (int m = 1; m < 64; m <<= 1) s += __shfl_xor(s, m, 64);
  const float den = fmaxf(sqrtf(s), 1e-12f);
  const float qx = v.x/den, qy = v.y/den, qz = v.z/den, qw = v.w/den;
  float t = qx*qx + qy*qy + qz*qz + qw*qw;
  #pragma unroll
  for (int m = 1; m < 64; m <<= 1) t += __shfl_xor(t, m, 64);
  if (lane == 0) { den_out[b] = den; cn2_out[b] = t; }
}

// ---------- prep 2: write cbn fp32 and cb16 fp16 (both row-major [k][256]) ----------
__global__ __launch_bounds__(64)
void prep_write2_kernel(const float* __restrict__ cb,
                        const float* __restrict__ den,
                        float* __restrict__ cbn,
                        _Float16* __restrict__ cb16) {
  const int b = blockIdx.x;
  const int lane = threadIdx.x;
  const float dn = den[b];
  float4 v = reinterpret_cast<const float4*>(cb + (size_t)b * D_DIM)[lane];
  v.x /= dn; v.y /= dn; v.z /= dn; v.w /= dn;     // true division = reference rounding
  reinterpret_cast<float4*>(cbn + (size_t)b * D_DIM)[lane] = v;
  half4v h;
  h[0] = (_Float16)v.x; h[1] = (_Float16)v.y; h[2] = (_Float16)v.z; h[3] = (_Float16)v.w;
  reinterpret_cast<half4v*>(cb16 + (size_t)b * D_DIM)[lane] = h;
}

// ---------- layer-0 residual fp16 ----------
__global__ __launch_bounds__(256)
void init16_kernel(const float* __restrict__ x, _Float16* __restrict__ R16) {
  const int i = blockIdx.x * 256 + threadIdx.x;   // 8 floats each
  const float4 a = ((const float4*)x)[(size_t)i*2+0];
  const float4 b = ((const float4*)x)[(size_t)i*2+1];
  half8 h;
  h[0]=(_Float16)a.x; h[1]=(_Float16)a.y; h[2]=(_Float16)a.z; h[3]=(_Float16)a.w;
  h[4]=(_Float16)b.x; h[5]=(_Float16)b.y; h[6]=(_Float16)b.z; h[7]=(_Float16)b.w;
  ((half8*)R16)[i] = h;
}

// ---------- per-layer: fp16 MFMA score GEMM + min/threshold candidate collect ----------
__global__ __launch_bounds__(256, 4)
void gemm_topk_kernel(const _Float16* __restrict__ A16,
                      const _Float16* __restrict__ B16,   // layer codebook fp16
                      const float* __restrict__ c2l,      // layer ||cbn||^2
                      float* __restrict__ cand_v,
                      int* __restrict__ cand_i,
                      int* __restrict__ cnt) {
  extern __shared__ char sm[];
  _Float16* As = (_Float16*)sm;                       // [128][72] fp16
  _Float16* Bs = As + 128*72;                         // [128][72] fp16
  float* minv   = (float*)(sm + 128*72*2*2);          // [128][2]
  float* thresh = minv + 256;                         // [128]

  const int tid = threadIdx.x;
  const int mt = blockIdx.x & 255, nt = blockIdx.x >> 8;
  const int ln = tid & 63, wid = tid >> 6;
  const int wm = wid >> 1, wn = wid & 1;

  f32x4 acc[4][4];
  #pragma unroll
  for (int i = 0; i < 4; ++i)
    #pragma unroll
    for (int j = 0; j < 4; ++j)
      #pragma unroll
      for (int e = 0; e < 4; ++e) acc[i][j][e] = 0.f;

  const _Float16* Ag = A16 + (size_t)(mt*128) * D_DIM;
  const _Float16* Bg = B16 + (size_t)(nt*128) * D_DIM;

  #pragma unroll 1
  for (int kt = 0; kt < 4; ++kt) {
    #pragma unroll
    for (int i = 0; i < 4; ++i) {
      const int c = tid + i*256, r = c >> 3, kb = c & 7;
      *(float4*)(As + r*72 + kb*8) = *(const float4*)(Ag + (size_t)r*D_DIM + kt*64 + kb*8);
      *(float4*)(Bs + r*72 + kb*8) = *(const float4*)(Bg + (size_t)r*D_DIM + kt*64 + kb*8);
    }
    __syncthreads();
    #pragma unroll
    for (int ks = 0; ks < 2; ++ks) {
      const int ko = ks*32 + (ln>>4)*8;
      half8 af[4], bf[4];
      #pragma unroll
      for (int f = 0; f < 4; ++f) {
        af[f] = *(const half8*)(As + (wm*64 + f*16 + (ln&15))*72 + ko);
        bf[f] = *(const half8*)(Bs + (wn*64 + f*16 + (ln&15))*72 + ko);
      }
      #pragma unroll
      for (int fm = 0; fm < 4; ++fm)
        #pragma unroll
        for (int fn = 0; fn < 4; ++fn)
          acc[fm][fn] = __builtin_amdgcn_mfma_f32_16x16x32_f16(af[fm], bf[fn], acc[fm][fn], 0, 0, 0);
    }
    __syncthreads();
  }

  // acc -> scores in place: s = c2 - 2*dot
  float c2r[4];
  #pragma unroll
  for (int fn = 0; fn < 4; ++fn) c2r[fn] = c2l[nt*128 + wn*64 + fn*16 + (ln&15)];
  #pragma unroll
  for (int fm = 0; fm < 4; ++fm)
    #pragma unroll
    for (int fn = 0; fn < 4; ++fn)
      #pragma unroll
      for (int rg = 0; rg < 4; ++rg)
        acc[fm][fn][rg] = fmaf(-2.f, acc[fm][fn][rg], c2r[fn]);

  // per-row tile-min: lane-local over fn, then butterfly over the 16-lane col group
  float rmin[16];
  #pragma unroll
  for (int fm = 0; fm < 4; ++fm)
    #pragma unroll
    for (int rg = 0; rg < 4; ++rg)
      rmin[fm*4+rg] = fminf(fminf(acc[fm][0][rg], acc[fm][1][rg]),
                            fminf(acc[fm][2][rg], acc[fm][3][rg]));
  #pragma unroll
  for (int m = 1; m < 16; m <<= 1)
    #pragma unroll
    for (int i = 0; i < 16; ++i)
      rmin[i] = fminf(rmin[i], __shfl_xor(rmin[i], m, 64));

  // one ds_write per lane (ln -> unique row of this wave's 64)
  {
    const int fm = ln & 3, rg = (ln >> 2) & 3, grp = ln >> 4;
    minv[(wm*64 + fm*16 + grp*4 + rg)*2 + wn] = rmin[fm*4+rg];
  }
  __syncthreads();
  if (tid < 128) thresh[tid] = fminf(minv[tid*2], minv[tid*2+1]) + DELTA;
  __syncthreads();

  float tr[16];
  #pragma unroll
  for (int fm = 0; fm < 4; ++fm)
    #pragma unroll
    for (int rg = 0; rg < 4; ++rg)
      tr[fm*4+rg] = thresh[wm*64 + fm*16 + (ln>>4)*4 + rg];

  // sparse collect: push (score,idx) for scores within DELTA of the tile min
  #pragma unroll
  for (int fm = 0; fm < 4; ++fm)
    #pragma unroll
    for (int rg = 0; rg < 4; ++rg) {
      const float t = tr[fm*4+rg];
      const int grow = mt*128 + wm*64 + fm*16 + (ln>>4)*4 + rg;
      #pragma unroll
      for (int fn = 0; fn < 4; ++fn) {
        const float s = acc[fm][fn][rg];
        if (s <= t) {
          const int slot = atomicAdd(&cnt[grow], 1);
          if (slot < CAP) {
            cand_v[(size_t)grow*CAP + slot] = s;
            cand_i[(size_t)grow*CAP + slot] = nt*128 + wn*64 + fn*16 + (ln&15);
          }
        }
      }
    }
}

// ---------- per-layer: filter candidates, exact double re-rank, update ----------
__global__ __launch_bounds__(256)
void merge_update_kernel(const int l,
                         const float* __restrict__ x,
                         const float* __restrict__ cb,
                         const float* __restrict__ cbn,
                         const float* __restrict__ c2,      // full [4][2048]
                         const float* __restrict__ cand_v,
                         const int* __restrict__ cand_i,
                         const int* __restrict__ cnt,
                         float* __restrict__ out_ids,
                         float* __restrict__ out_dec,
                         _Float16* __restrict__ R16,
                         double* __restrict__ dloss) {
  __shared__ int idxs[64][8];
  __shared__ int mcnt[64];
  __shared__ double lw[4];
  const int tid = threadIdx.x;
  const int row0 = blockIdx.x * 64;

  // phase 1: min over collected approx scores, keep those within DELTA2
  if (tid < 64) {
    const int row = row0 + tid;
    int c = cnt[row]; c = c > CAP ? CAP : c;
    const float* vp = cand_v + (size_t)row*CAP;
    const int*   ip = cand_i + (size_t)row*CAP;
    float vmin = INFINITY;
    for (int j = 0; j < c; ++j) vmin = fminf(vmin, vp[j]);
    const float lim = vmin + DELTA2;
    int M = 0;
    for (int j = 0; j < c && M < 8; ++j)
      if (vp[j] <= lim) idxs[tid][M++] = ip[j];
    mcnt[tid] = M;
  }
  __syncthreads();

  // phase 2: recompute fp32 residual exactly (sequential subtraction = ref rounding)
  const int rt = tid >> 2, qo = (tid & 3) * 64;
  const int row = row0 + rt;
  float r[64];
  {
    const float4* xg = (const float4*)(x + (size_t)row*D_DIM + qo);
    #pragma unroll
    for (int i = 0; i < 16; ++i) {
      const float4 a = xg[i];
      r[i*4+0]=a.x; r[i*4+1]=a.y; r[i*4+2]=a.z; r[i*4+3]=a.w;
    }
  }
  #pragma unroll 1
  for (int j = 0; j < l; ++j) {
    const int pj = (int)out_ids[(size_t)row*L_NUM + j];
    const float4* qg = (const float4*)(cb + ((size_t)j*K_CB + pj)*D_DIM + qo);
    #pragma unroll
    for (int i = 0; i < 16; ++i) {
      const float4 a = qg[i];
      r[i*4+0]-=a.x; r[i*4+1]-=a.y; r[i*4+2]-=a.z; r[i*4+3]-=a.w;
    }
  }

  // phase 3: exact double re-rank of the filtered candidates (usually 1-2)
  const int M = mcnt[rt];
  double bs = (double)INFINITY; int bi = 0x7fffffff;
  #pragma unroll 1
  for (int c = 0; c < M; ++c) {
    const int cidx = idxs[rt][c];
    const float4* cp = (const float4*)(cbn + ((size_t)l*K_CB + cidx)*D_DIM + qo);
    double s = 0.0;
    #pragma unroll
    for (int i = 0; i < 16; ++i) {
      const float4 a = cp[i];
      s = fma((double)r[i*4+0], (double)a.x, s);
      s = fma((double)r[i*4+1], (double)a.y, s);
      s = fma((double)r[i*4+2], (double)a.z, s);
      s = fma((double)r[i*4+3], (double)a.w, s);
    }
    s += __shfl_xor(s, 1, 64);
    s += __shfl_xor(s, 2, 64);
    const double sc = -2.0 * s + (double)c2[l*K_CB + cidx];
    if (sc < bs || (sc == bs && cidx < bi)) { bs = sc; bi = cidx; }
  }
  if ((tid & 3) == 0) out_ids[(size_t)row*L_NUM + l] = (float)bi;

  // phase 4: gather RAW codeword; decoded += q; r_new = r - q; loss; R16 for next layer
  double lloss = 0.0;
  {
    const float4* qg = (const float4*)(cb + ((size_t)l*K_CB + bi)*D_DIM + qo);
    float4* dg = (float4*)(out_dec + (size_t)row*D_DIM + qo);
    _Float16* rg = R16 + (size_t)row*D_DIM + qo;
    #pragma unroll
    for (int i = 0; i < 8; ++i) {     // 8 dims per iter
      const float4 q0 = qg[i*2+0], q1 = qg[i*2+1];
      float rn[8];
      rn[0]=r[i*8+0]-q0.x; rn[1]=r[i*8+1]-q0.y; rn[2]=r[i*8+2]-q0.z; rn[3]=r[i*8+3]-q0.w;
      rn[4]=r[i*8+4]-q1.x; rn[5]=r[i*8+5]-q1.y; rn[6]=r[i*8+6]-q1.z; rn[7]=r[i*8+7]-q1.w;
      float4 d0, d1;
      if (l == 0) { d0 = q0; d1 = q1; }
      else {
        d0 = dg[i*2+0]; d0.x+=q0.x; d0.y+=q0.y; d0.z+=q0.z; d0.w+=q0.w;
        d1 = dg[i*2+1]; d1.x+=q1.x; d1.y+=q1.y; d1.z+=q1.z; d1.w+=q1.w;
      }
      dg[i*2+0] = d0; dg[i*2+1] = d1;
      lloss += (double)rn[0]*rn[0] + (double)rn[1]*rn[1]
             + (double)rn[2]*rn[2] + (double)rn[3]*rn[3]
             + (double)rn[4]*rn[4] + (double)rn[5]*rn[5]
             + (double)rn[6]*rn[6] + (double)rn[7]*rn[7];
      if (l < 3) {
        half8 h;
        h[0]=(_Float16)rn[0]; h[1]=(_Float16)rn[1]; h[2]=(_Float16)rn[2]; h[3]=(_Float16)rn[3];
        h[4]=(_Float16)rn[4]; h[5]=(_Float16)rn[5]; h[6]=(_Float16)rn[6]; h[7]=(_Float16)rn[7];
        *(half8*)(rg + i*8) = h;
      }
    }
  }
  #pragma unroll
  for (int m = 1; m < 64; m <<= 1) lloss += __shfl_xor(lloss, m, 64);
  if ((tid & 63) == 0) lw[tid >> 6] = lloss;
  __syncthreads();
  if (tid == 0) atomicAdd(dloss, lw[0]+lw[1]+lw[2]+lw[3]);
}

__global__ void rq_fin_kernel(const double* __restrict__ dls, float* __restrict__ out_loss) {
  // loss = sum_l (1 + BETA) * ||r-q||^2 / n_elem  (codebook and commitment terms equal)
  out_loss[0] = (float)(dls[0] * 1.25 / 8388608.0);
}

extern "C" void kernel_launch(void* const* d_in, const int* in_sizes, int n_in,
                              void* d_out, int out_size, void* d_ws, size_t ws_size,
                              hipStream_t stream) {
  const float* x  = (const float*)d_in[0];
  const float* cb = (const float*)d_in[1];
  float* out      = (float*)d_out;
  float* out_ids  = out;                                   // [N][4] as float
  float* out_dec  = out + (size_t)N_ROWS * L_NUM;          // [N][256]
  float* out_loss = out_dec + (size_t)N_ROWS * D_DIM;

  char* w = (char*)d_ws;
  float* den = (float*)w;                     w += (size_t)L_NUM*K_CB*4;
  float* c2  = (float*)w;                     w += (size_t)L_NUM*K_CB*4;
  double* dls = (double*)w;                   w += 256;
  float* cbn = (float*)w;                     w += (size_t)L_NUM*K_CB*D_DIM*4;
  _Float16* cb16 = (_Float16*)w;              w += (size_t)L_NUM*K_CB*D_DIM*2;
  _Float16* R16 = (_Float16*)w;               w += (size_t)N_ROWS*D_DIM*2;
  float* cand_v = (float*)w;                  w += (size_t)N_ROWS*CAP*4;
  int* cand_i = (int*)w;                      w += (size_t)N_ROWS*CAP*4;
  int* cnt = (int*)w;                         w += (size_t)N_ROWS*4;

  hipMemsetAsync(dls, 0, sizeof(double), stream);
  prep_norm_kernel<<<L_NUM*K_CB, 64, 0, stream>>>(cb, den, c2);
  prep_write2_kernel<<<L_NUM*K_CB, 64, 0, stream>>>(cb, den, cbn, cb16);
  init16_kernel<<<(N_ROWS*D_DIM/8 + 255)/256, 256, 0, stream>>>(x, R16);

  const size_t smem = 128*72*2*2 + 256*4 + 128*4;   // 38400 B
  hipFuncSetAttribute(reinterpret_cast<const void*>(gemm_topk_kernel),
                      hipFuncAttributeMaxDynamicSharedMemorySize, (int)smem);

  for (int l = 0; l < L_NUM; ++l) {
    hipMemsetAsync(cnt, 0, (size_t)N_ROWS*4, stream);
    gemm_topk_kernel<<<4096, 256, smem, stream>>>(
        R16, cb16 + (size_t)l*K_CB*D_DIM, c2 + l*K_CB, cand_v, cand_i, cnt);
    merge_update_kernel<<<N_ROWS/64, 256, 0, stream>>>(
        l, x, cb, cbn, c2, cand_v, cand_i, cnt, out_ids, out_dec, R16, dls);
  }
  rq_fin_kernel<<<1, 1, 0, stream>>>(dls, out_loss);
}

// Round 4
// 478.926 us; speedup vs baseline: 7.9506x; 1.4622x over previous
//
#include <hip/hip_runtime.h>
#include <math.h>

#define L_NUM 4
#define K_CB  2048
#define D_DIM 256
#define N_ROWS 32768
#define CAP 56            // packed candidate slots per row (LDS + global)
#define WACC  0.08f       // collect window on dot values (fp16 worst-case err bound 0.078)
#define WACC2 0.095f      // merge filter window (> WACC collect guarantee)

typedef _Float16 half8 __attribute__((ext_vector_type(8)));
typedef _Float16 half4v __attribute__((ext_vector_type(4)));
typedef float f32x16 __attribute__((ext_vector_type(16)));

__device__ __forceinline__ void gl_lds16(const void* g, void* l) {
  __builtin_amdgcn_global_load_lds(
      (const __attribute__((address_space(1))) void*)g,
      (__attribute__((address_space(3))) void*)l, 16, 0, 0);
}

// monotone float<->uint encoding for atomicMax on floats
__device__ __forceinline__ unsigned fenc(float f) {
  unsigned u = __float_as_uint(f);
  return (u & 0x80000000u) ? ~u : (u | 0x80000000u);
}
__device__ __forceinline__ float fdec(unsigned k) {
  unsigned u = (k & 0x80000000u) ? (k ^ 0x80000000u) : ~k;
  return __uint_as_float(u);
}

// ---------- prep: per-codeword norm, c2, cbn fp32, cb16 fp16 (SWIZZLED rows) ----------
__global__ __launch_bounds__(64)
void prep_all_kernel(const float* __restrict__ cb,
                     float* __restrict__ c2,
                     float* __restrict__ cbn,
                     _Float16* __restrict__ cb16) {
  const int b = blockIdx.x;            // l*K + k
  const int lane = threadIdx.x;        // 0..63, 4 elems each
  float4 v = reinterpret_cast<const float4*>(cb + (size_t)b * D_DIM)[lane];
  float s = v.x*v.x + v.y*v.y + v.z*v.z + v.w*v.w;
  #pragma unroll
  for (int m = 1; m < 64; m <<= 1) s += __shfl_xor(s, m, 64);
  const float den = fmaxf(sqrtf(s), 1e-12f);
  v.x /= den; v.y /= den; v.z /= den; v.w /= den;   // true division = reference rounding
  reinterpret_cast<float4*>(cbn + (size_t)b * D_DIM)[lane] = v;
  half4v h;
  h[0] = (_Float16)v.x; h[1] = (_Float16)v.y; h[2] = (_Float16)v.z; h[3] = (_Float16)v.w;
  // swizzle: 16B slot (lane>>1) -> slot ^ (row&7); 8B half = lane&1
  reinterpret_cast<half4v*>(cb16 + (size_t)b * D_DIM)[(((lane>>1) ^ (b&7)) << 1) | (lane&1)] = h;
  float t = v.x*v.x + v.y*v.y + v.z*v.z + v.w*v.w;
  #pragma unroll
  for (int m = 1; m < 64; m <<= 1) t += __shfl_xor(t, m, 64);
  if (lane == 0) c2[b] = t;
}

// ---------- layer-0 residual fp16 (swizzled) ----------
__global__ __launch_bounds__(256)
void init16_kernel(const float* __restrict__ x, _Float16* __restrict__ R16) {
  const int id = blockIdx.x * 256 + threadIdx.x;  // one half8 (16B slot) each
  const int row = id >> 5, slot = id & 31;
  const float4 a = ((const float4*)x)[(size_t)row*64 + slot*2];
  const float4 b = ((const float4*)x)[(size_t)row*64 + slot*2 + 1];
  half8 h;
  h[0]=(_Float16)a.x; h[1]=(_Float16)a.y; h[2]=(_Float16)a.z; h[3]=(_Float16)a.w;
  h[4]=(_Float16)b.x; h[5]=(_Float16)b.y; h[6]=(_Float16)b.z; h[7]=(_Float16)b.w;
  ((half8*)(R16 + (size_t)row*D_DIM))[slot ^ (row&7)] = h;
}

// ---------- per-layer: A-resident MFMA GEMM over all 2048 cols + lane-local collect ----------
__global__ __launch_bounds__(256, 1)
void gemm_cand_kernel(const _Float16* __restrict__ A16,   // swizzled residual fp16
                      const _Float16* __restrict__ B16,   // swizzled layer codebook fp16
                      float* __restrict__ rowapx,         // [N] final approx dot-max
                      unsigned* __restrict__ cand_p,      // [N][CAP] packed (q<<11|idx)
                      int* __restrict__ cand_n) {         // [N]
  extern __shared__ char sm[];
  _Float16* As = (_Float16*)sm;                    // [128 rows][256 K]  64 KB
  _Float16* Bs = (_Float16*)(sm + 65536);          // 2 x [128 cols][128 K] 32 KB each
  unsigned* cp = (unsigned*)(sm + 131072);         // [128][CAP]
  int* cn      = (int*)(sm + 131072 + 128*CAP*4);  // [128]
  unsigned* rmx = (unsigned*)((char*)cn + 512);    // [128]

  const int tid = threadIdx.x;
  const int mt = blockIdx.x;
  const int ln = tid & 63, wid = tid >> 6;
  const int wm = wid >> 1, wn = wid & 1;
  const int l31 = ln & 31, hl = ln >> 5, xr = l31 & 7;

  if (tid < 128) { cn[tid] = 0; rmx[tid] = 0u; }

  // stage A once: pure linear copy (swizzle baked into global image)
  const char* Ag = (const char*)A16 + (size_t)mt * 65536;
  #pragma unroll
  for (int i = 0; i < 16; ++i) {
    const int off = tid*16 + i*4096;
    gl_lds16(Ag + off, (char*)As + off);
  }

  const char* Bg = (const char*)B16;
  auto stageB = [&](int s) {
    const int ct = s >> 1, kh = s & 1;
    char* dst = (char*)Bs + (s & 1) * 32768;
    #pragma unroll
    for (int i = 0; i < 8; ++i) {
      const int lin = tid*16 + i*4096;           // [0,32768)
      const int c = lin >> 8, w = lin & 255;
      gl_lds16(Bg + (size_t)ct*65536 + (size_t)c*512 + kh*256 + w, dst + lin);
    }
  };

  stageB(0);
  __syncthreads();

  f32x16 acc[2][2];
  float rmax[2] = {-INFINITY, -INFINITY};

  #pragma unroll 1
  for (int s = 0; s < 32; ++s) {
    const int ct = s >> 1, kh = s & 1;
    if (s < 31) stageB(s + 1);                   // prefetch next half-tile
    if (kh == 0) {
      #pragma unroll
      for (int bi = 0; bi < 2; ++bi)
        #pragma unroll
        for (int ai = 0; ai < 2; ++ai)
          #pragma unroll
          for (int e = 0; e < 16; ++e) acc[bi][ai][e] = 0.f;
    }
    const _Float16* Bb = Bs + (s & 1) * 16384;
    #pragma unroll
    for (int ksl = 0; ksl < 8; ++ksl) {
      const int ks = kh*8 + ksl;
      half8 af[2], bf[2];
      #pragma unroll
      for (int ai = 0; ai < 2; ++ai) {
        const int row = wm*64 + ai*32 + l31;
        af[ai] = ((const half8*)As)[row*32 + ((ks*2 + hl) ^ xr)];
      }
      #pragma unroll
      for (int bi = 0; bi < 2; ++bi) {
        const int col = wn*64 + bi*32 + l31;
        bf[bi] = ((const half8*)Bb)[col*16 + ((ksl*2 + hl) ^ xr)];
      }
      // swapped operands: reg dim = codebook col, lane dim = data row
      acc[0][0] = __builtin_amdgcn_mfma_f32_32x32x16_f16(bf[0], af[0], acc[0][0], 0, 0, 0);
      acc[0][1] = __builtin_amdgcn_mfma_f32_32x32x16_f16(bf[0], af[1], acc[0][1], 0, 0, 0);
      acc[1][0] = __builtin_amdgcn_mfma_f32_32x32x16_f16(bf[1], af[0], acc[1][0], 0, 0, 0);
      acc[1][1] = __builtin_amdgcn_mfma_f32_32x32x16_f16(bf[1], af[1], acc[1][1], 0, 0, 0);
    }
    if (kh == 1) {
      // epilogue for col-tile ct: running max + threshold collect (all lane-local)
      #pragma unroll
      for (int ai = 0; ai < 2; ++ai) {
        const int row = wm*64 + ai*32 + l31;
        float m = rmax[ai];
        #pragma unroll
        for (int bi = 0; bi < 2; ++bi)
          #pragma unroll
          for (int rg = 0; rg < 16; ++rg)
            m = fmaxf(m, acc[bi][ai][rg]);
        rmax[ai] = m;
        atomicMax(&rmx[row], fenc(m));
        const float thr = fmaxf(m, fdec(rmx[row])) - WACC;   // stale-read safe (superset)
        #pragma unroll
        for (int bi = 0; bi < 2; ++bi) {
          const int cbase = ct*128 + wn*64 + bi*32 + hl*4;
          #pragma unroll
          for (int rg = 0; rg < 16; ++rg) {
            const float v = acc[bi][ai][rg];
            if (v >= thr) {
              const int slot = atomicAdd(&cn[row], 1);
              if (slot < CAP) {
                const unsigned q = (unsigned)((v + 64.f) * 16384.f);   // monotone, res 6e-5
                cp[row*CAP + slot] = (q << 11) | (unsigned)(cbase + (rg&3) + 8*(rg>>2));
              }
            }
          }
        }
      }
    }
    __syncthreads();
  }

  if (tid < 128) {
    const int grow = mt*128 + tid;
    const int n = min(cn[tid], CAP);
    cand_n[grow] = n;
    rowapx[grow] = fdec(rmx[tid]);
    for (int j = 0; j < n; ++j)
      cand_p[(size_t)grow*CAP + j] = cp[tid*CAP + j];
  }
}

// ---------- per-layer: filter candidates, exact double re-rank, update ----------
__global__ __launch_bounds__(256)
void merge_update_kernel(const int l,
                         const float* __restrict__ x,
                         const float* __restrict__ cb,
                         const float* __restrict__ cbn,
                         const float* __restrict__ c2,
                         const float* __restrict__ rowapx,
                         const unsigned* __restrict__ cand_p,
                         const int* __restrict__ cand_n,
                         float* __restrict__ out_ids,
                         float* __restrict__ out_dec,
                         _Float16* __restrict__ R16,
                         double* __restrict__ dloss) {
  __shared__ int idxs[64][8];
  __shared__ int mcnt[64];
  __shared__ double lw[4];
  const int tid = threadIdx.x;
  const int row0 = blockIdx.x * 64;

  // phase 1: filter collected candidates by approx-max window
  if (tid < 64) {
    const int row = row0 + tid;
    const float thr = rowapx[row] - WACC2;
    const int n = cand_n[row];
    const unsigned* pp = cand_p + (size_t)row * CAP;
    int M = 0;
    #pragma unroll 1
    for (int j = 0; j < n && M < 8; ++j) {
      const unsigned p = pp[j];
      const float v = (float)(p >> 11) * (1.f/16384.f) - 64.f;
      if (v >= thr) idxs[tid][M++] = (int)(p & 2047u);
    }
    mcnt[tid] = M;
  }
  __syncthreads();

  // phase 2: recompute fp32 residual exactly (sequential subtraction = ref rounding)
  const int rt = tid >> 2, qo = (tid & 3) * 64;
  const int row = row0 + rt;
  float r[64];
  {
    const float4* xg = (const float4*)(x + (size_t)row*D_DIM + qo);
    #pragma unroll
    for (int i = 0; i < 16; ++i) {
      const float4 a = xg[i];
      r[i*4+0]=a.x; r[i*4+1]=a.y; r[i*4+2]=a.z; r[i*4+3]=a.w;
    }
  }
  #pragma unroll 1
  for (int j = 0; j < l; ++j) {
    const int pj = (int)out_ids[(size_t)row*L_NUM + j];
    const float4* qg = (const float4*)(cb + ((size_t)j*K_CB + pj)*D_DIM + qo);
    #pragma unroll
    for (int i = 0; i < 16; ++i) {
      const float4 a = qg[i];
      r[i*4+0]-=a.x; r[i*4+1]-=a.y; r[i*4+2]-=a.z; r[i*4+3]-=a.w;
    }
  }

  // phase 3: exact double re-rank of the surviving candidates (usually 1-2)
  const int M = mcnt[rt];
  double bs = (double)INFINITY; int bsti = 0x7fffffff;
  #pragma unroll 1
  for (int c = 0; c < M; ++c) {
    const int cidx = idxs[rt][c];
    const float4* cp4 = (const float4*)(cbn + ((size_t)l*K_CB + cidx)*D_DIM + qo);
    double s = 0.0;
    #pragma unroll
    for (int i = 0; i < 16; ++i) {
      const float4 a = cp4[i];
      s = fma((double)r[i*4+0], (double)a.x, s);
      s = fma((double)r[i*4+1], (double)a.y, s);
      s = fma((double)r[i*4+2], (double)a.z, s);
      s = fma((double)r[i*4+3], (double)a.w, s);
    }
    s += __shfl_xor(s, 1, 64);
    s += __shfl_xor(s, 2, 64);
    const double sc = -2.0 * s + (double)c2[l*K_CB + cidx];
    if (sc < bs || (sc == bs && cidx < bsti)) { bs = sc; bsti = cidx; }
  }
  if ((tid & 3) == 0) out_ids[(size_t)row*L_NUM + l] = (float)bsti;

  // phase 4: gather RAW codeword; r_new = r - q; loss; R16 (l<3, swizzled) or dec (l==3)
  double lloss = 0.0;
  {
    const float4* qg = (const float4*)(cb + ((size_t)l*K_CB + bsti)*D_DIM + qo);
    _Float16* rg16 = R16 + (size_t)row*D_DIM;
    float4* dg = (float4*)(out_dec + (size_t)row*D_DIM + qo);
    const float4* xg2 = (const float4*)(x + (size_t)row*D_DIM + qo);
    const int slotb = (tid & 3) * 8;
    #pragma unroll
    for (int i = 0; i < 8; ++i) {     // 8 dims per iter
      const float4 q0 = qg[i*2+0], q1 = qg[i*2+1];
      float rn[8];
      rn[0]=r[i*8+0]-q0.x; rn[1]=r[i*8+1]-q0.y; rn[2]=r[i*8+2]-q0.z; rn[3]=r[i*8+3]-q0.w;
      rn[4]=r[i*8+4]-q1.x; rn[5]=r[i*8+5]-q1.y; rn[6]=r[i*8+6]-q1.z; rn[7]=r[i*8+7]-q1.w;
      lloss += (double)rn[0]*rn[0] + (double)rn[1]*rn[1]
             + (double)rn[2]*rn[2] + (double)rn[3]*rn[3]
             + (double)rn[4]*rn[4] + (double)rn[5]*rn[5]
             + (double)rn[6]*rn[6] + (double)rn[7]*rn[7];
      if (l < 3) {
        half8 h;
        h[0]=(_Float16)rn[0]; h[1]=(_Float16)rn[1]; h[2]=(_Float16)rn[2]; h[3]=(_Float16)rn[3];
        h[4]=(_Float16)rn[4]; h[5]=(_Float16)rn[5]; h[6]=(_Float16)rn[6]; h[7]=(_Float16)rn[7];
        ((half8*)rg16)[(slotb + i) ^ (row&7)] = h;
      } else {
        const float4 xa = xg2[i*2+0], xb = xg2[i*2+1];
        dg[i*2+0] = make_float4(xa.x-rn[0], xa.y-rn[1], xa.z-rn[2], xa.w-rn[3]);
        dg[i*2+1] = make_float4(xb.x-rn[4], xb.y-rn[5], xb.z-rn[6], xb.w-rn[7]);
      }
    }
  }
  #pragma unroll
  for (int m = 1; m < 64; m <<= 1) lloss += __shfl_xor(lloss, m, 64);
  if ((tid & 63) == 0) lw[tid >> 6] = lloss;
  __syncthreads();
  if (tid == 0) atomicAdd(dloss, lw[0]+lw[1]+lw[2]+lw[3]);
}

__global__ void rq_fin_kernel(const double* __restrict__ dls, float* __restrict__ out_loss) {
  // loss = sum_l (1 + BETA) * ||r-q||^2 / n_elem  (codebook and commitment terms equal)
  out_loss[0] = (float)(dls[0] * 1.25 / 8388608.0);
}

extern "C" void kernel_launch(void* const* d_in, const int* in_sizes, int n_in,
                              void* d_out, int out_size, void* d_ws, size_t ws_size,
                              hipStream_t stream) {
  const float* x  = (const float*)d_in[0];
  const float* cb = (const float*)d_in[1];
  float* out      = (float*)d_out;
  float* out_ids  = out;                                   // [N][4] as float
  float* out_dec  = out + (size_t)N_ROWS * L_NUM;          // [N][256]
  float* out_loss = out_dec + (size_t)N_ROWS * D_DIM;

  char* w = (char*)d_ws;
  double* dls = (double*)w;                   w += 256;
  float* c2  = (float*)w;                     w += (size_t)L_NUM*K_CB*4;
  float* cbn = (float*)w;                     w += (size_t)L_NUM*K_CB*D_DIM*4;
  _Float16* cb16 = (_Float16*)w;              w += (size_t)L_NUM*K_CB*D_DIM*2;
  _Float16* R16 = (_Float16*)w;               w += (size_t)N_ROWS*D_DIM*2;
  float* rowapx = (float*)w;                  w += (size_t)N_ROWS*4;
  int* cand_n = (int*)w;                      w += (size_t)N_ROWS*4;
  unsigned* cand_p = (unsigned*)w;            w += (size_t)N_ROWS*CAP*4;

  hipMemsetAsync(dls, 0, sizeof(double), stream);
  prep_all_kernel<<<L_NUM*K_CB, 64, 0, stream>>>(cb, c2, cbn, cb16);
  init16_kernel<<<N_ROWS*32/256, 256, 0, stream>>>(x, R16);

  const size_t smem = 65536 + 65536 + 128*CAP*4 + 512 + 512;   // 160768 B
  hipFuncSetAttribute(reinterpret_cast<const void*>(gemm_cand_kernel),
                      hipFuncAttributeMaxDynamicSharedMemorySize, (int)smem);

  for (int l = 0; l < L_NUM; ++l) {
    gemm_cand_kernel<<<256, 256, smem, stream>>>(
        R16, cb16 + (size_t)l*K_CB*D_DIM, rowapx, cand_p, cand_n);
    merge_update_kernel<<<N_ROWS/64, 256, 0, stream>>>(
        l, x, cb, cbn, c2, rowapx, cand_p, cand_n, out_ids, out_dec, R16, dls);
  }
  rq_fin_kernel<<<1, 1, 0, stream>>>(dls, out_loss);
}

// Round 6
// 345.114 us; speedup vs baseline: 11.0333x; 1.3877x over previous
//
#include <hip/hip_runtime.h>
#include <math.h>

#define L_NUM 4
#define K_CB  2048
#define D_DIM 256
#define N_ROWS 32768
#define CAP 56            // per-row candidate slots (LDS)
#define WACC  0.12f       // collect window (>= 2x worst-case fp16 dot err ~0.032)
#define WACC2 0.125f      // filter window (collect + packing quantization margin)

typedef _Float16 half8 __attribute__((ext_vector_type(8)));
typedef _Float16 half4v __attribute__((ext_vector_type(4)));
typedef float f32x16 __attribute__((ext_vector_type(16)));

__device__ __forceinline__ void gl_lds16(const void* g, void* l) {
  __builtin_amdgcn_global_load_lds(
      (const __attribute__((address_space(1))) void*)g,
      (__attribute__((address_space(3))) void*)l, 16, 0, 0);
}
// monotone float<->uint encoding for atomicMax on floats
__device__ __forceinline__ unsigned fenc(float f) {
  unsigned u = __float_as_uint(f);
  return (u & 0x80000000u) ? ~u : (u | 0x80000000u);
}
__device__ __forceinline__ float fdec(unsigned k) {
  unsigned u = (k & 0x80000000u) ? (k ^ 0x80000000u) : ~k;
  return __uint_as_float(u);
}

// ---------- prep: cbn fp32 (row-major) + cb16 image, K-slot-major chunks ----------
// image chunk c (32 per layer) = cols [ (c>>3)*512 .. +512 ), K-halves [ (c&7)*32 .. +32 )
// within chunk: [s in 0..4)][col 0..512)[8 halves]  (s = 8-half K-subslot)
__global__ __launch_bounds__(64)
void prep_all_kernel(const float* __restrict__ cb,
                     float* __restrict__ cbn,
                     _Float16* __restrict__ cb16) {
  const int b = blockIdx.x;            // l*2048 + k
  const int k = b & 2047, l = b >> 11;
  const int lane = threadIdx.x;        // 4 dims each
  float4 v = reinterpret_cast<const float4*>(cb + (size_t)b * D_DIM)[lane];
  float s = v.x*v.x + v.y*v.y + v.z*v.z + v.w*v.w;
  #pragma unroll
  for (int m = 1; m < 64; m <<= 1) s += __shfl_xor(s, m, 64);
  const float den = fmaxf(sqrtf(s), 1e-12f);
  v.x /= den; v.y /= den; v.z /= den; v.w /= den;   // true division = reference rounding
  reinterpret_cast<float4*>(cbn + (size_t)b * D_DIM)[lane] = v;
  half4v h;
  h[0] = (_Float16)v.x; h[1] = (_Float16)v.y; h[2] = (_Float16)v.z; h[3] = (_Float16)v.w;
  const int tile = k >> 9, col = k & 511;
  const int kchunk = lane >> 3;            // dim/32
  const int sslot  = (lane >> 1) & 3;      // (dim&31)/8
  const int rem    = (lane & 1) * 4;       // dim&7
  const size_t off = (size_t)l * (K_CB * D_DIM)
                   + (size_t)(tile * 8 + kchunk) * 16384
                   + (size_t)sslot * 4096 + (size_t)col * 8 + rem;
  *(half4v*)(cb16 + off) = h;
}

// ---------- fused: 128 rows/block resident, 4 layers, GEMM+collect+exact re-rank ----------
__global__ __launch_bounds__(512, 2)
void rq_fused_kernel(const float* __restrict__ x,
                     const float* __restrict__ cb,
                     const float* __restrict__ cbn,
                     const _Float16* __restrict__ cb16,
                     float* __restrict__ out_ids,
                     float* __restrict__ out_dec,
                     double* __restrict__ dloss) {
  extern __shared__ char sm[];
  _Float16* A16   = (_Float16*)sm;                     // [32 Kslots][128 rows][8h] 64 KB
  _Float16* Bs    = (_Float16*)(sm + 65536);           // 2 x [4 s][512 cols][8h] 32 KB each
  unsigned* cp    = (unsigned*)(sm + 131072);          // [128][CAP] packed (q<<11|idx)
  int*      cn    = (int*)(sm + 131072 + 128*CAP*4);   // [128]
  unsigned* gmax  = (unsigned*)((char*)cn + 512);      // [128] running approx max (fenc)
  unsigned* bestp = (unsigned*)((char*)gmax + 512);    // [128] best packed (fallback)

  const int t = threadIdx.x;
  const int wid = t >> 6, ln = t & 63;
  const int l31 = ln & 31, hl = ln >> 5;
  const int rowg = wid >> 2, colg = wid & 3;           // 2 row-groups x 4 col-groups
  const int urow = t >> 2, qo = (t & 3) * 64;          // r-owner mapping: 4 thr/row
  const int row0 = blockIdx.x * 128;
  const int mrow0 = rowg * 64 + l31, mrow1 = mrow0 + 32;

  // ---- load x quarter into r regs; build A16 (layer-0 input) ----
  float r[64];
  {
    const float4* xg = (const float4*)(x + (size_t)(row0 + urow) * D_DIM + qo);
    #pragma unroll
    for (int i = 0; i < 16; ++i) {
      const float4 a = xg[i];
      r[i*4+0]=a.x; r[i*4+1]=a.y; r[i*4+2]=a.z; r[i*4+3]=a.w;
    }
  }
  #pragma unroll
  for (int j = 0; j < 8; ++j) {
    half8 h;
    #pragma unroll
    for (int e = 0; e < 8; ++e) h[e] = (_Float16)r[j*8+e];
    const int slot = (t & 3) * 8 + j;                  // global K-slot
    *(half8*)(A16 + slot*1024 + urow*8) = h;
  }
  if (t < 128) { cn[t] = 0; gmax[t] = 0u; bestp[t] = 0u; }
  int id0 = 0, id1 = 0, id2 = 0, id3 = 0;
  double lloss = 0.0;

  #pragma unroll 1
  for (int l = 0; l < L_NUM; ++l) {
    const char* Bimg = (const char*)cb16 + (size_t)l * (K_CB * D_DIM * 2);
    {
      char* dst = (char*)Bs;
      #pragma unroll
      for (int i = 0; i < 4; ++i)
        gl_lds16(Bimg + t*16 + i*8192, dst + t*16 + i*8192);
    }
    __syncthreads();   // A16 ready (l=0: init; l>0: tail rebuild), resets visible, chunk0 in

    f32x16 acc[4][2];  // [bi][ai], all indices compile-time (fully unrolled)

    #pragma unroll 1
    for (int g = 0; g < 32; ++g) {
      if ((g & 7) == 0) {
        #pragma unroll
        for (int bi = 0; bi < 4; ++bi)
          #pragma unroll
          for (int ai = 0; ai < 2; ++ai)
            #pragma unroll
            for (int e = 0; e < 16; ++e) acc[bi][ai][e] = 0.f;
      }
      if (g < 31) {                      // prefetch next chunk into other buffer
        char* dst = (char*)Bs + ((g + 1) & 1) * 32768;
        const char* src = Bimg + (size_t)(g + 1) * 32768;
        #pragma unroll
        for (int i = 0; i < 4; ++i)
          gl_lds16(src + t*16 + i*8192, dst + t*16 + i*8192);
      }
      const _Float16* Bb = Bs + (g & 1) * 16384;
      const int cK = g & 7;
      #pragma unroll
      for (int ks2 = 0; ks2 < 2; ++ks2) {
        const int sa = cK*4 + ks2*2 + hl;              // global K-subslot for A
        const int sb = ks2*2 + hl;                     // chunk-local for B
        half8 af[2], bf[4];
        af[0] = *(const half8*)(A16 + sa*1024 + mrow0*8);
        af[1] = *(const half8*)(A16 + sa*1024 + mrow1*8);
        #pragma unroll
        for (int bi = 0; bi < 4; ++bi) {
          const int col = colg*128 + bi*32 + l31;
          bf[bi] = *(const half8*)(Bb + sb*4096 + col*8);
        }
        #pragma unroll
        for (int bi = 0; bi < 4; ++bi) {
          acc[bi][0] = __builtin_amdgcn_mfma_f32_32x32x16_f16(bf[bi], af[0], acc[bi][0], 0, 0, 0);
          acc[bi][1] = __builtin_amdgcn_mfma_f32_32x32x16_f16(bf[bi], af[1], acc[bi][1], 0, 0, 0);
        }
      }
      if ((g & 7) == 7) {                // epilogue per 512-col tile (lane-local rows)
        const int ct = g >> 3;
        #pragma unroll
        for (int ai = 0; ai < 2; ++ai) {
          const int mrow = ai ? mrow1 : mrow0;
          float m = -INFINITY;
          #pragma unroll
          for (int bi = 0; bi < 4; ++bi)
            #pragma unroll
            for (int rg = 0; rg < 16; ++rg) m = fmaxf(m, acc[bi][ai][rg]);
          atomicMax(&gmax[mrow], fenc(m));
          const float thr = fdec(gmax[mrow]) - WACC;   // >= own m - WACC; stale=superset-safe
          #pragma unroll
          for (int bi = 0; bi < 4; ++bi)
            #pragma unroll
            for (int rg = 0; rg < 16; ++rg) {
              const float v = acc[bi][ai][rg];
              if (v >= thr) {
                const unsigned q = (unsigned)((v + 64.f) * 16384.f);   // monotone pack
                const unsigned cidx = (unsigned)(ct*512 + colg*128 + bi*32
                                                 + 4*hl + (rg & 3) + 8*(rg >> 2));
                const unsigned pk = (q << 11) | cidx;
                atomicMax(&bestp[mrow], pk);           // unconditional fallback
                const int slot = atomicAdd(&cn[mrow], 1);
                if (slot < CAP) cp[mrow*CAP + slot] = pk;
              }
            }
        }
      }
      __syncthreads();
    }

    // ---- tail: filter + exact double re-rank + residual/loss update ----
    {
      const float thr2 = fdec(gmax[urow]) - WACC2;
      const int m = min(cn[urow], CAP);
      double bsc = (double)INFINITY; int bidx = 0x7fffffff;
      #pragma unroll 1
      for (int j = 0; j <= m; ++j) {                   // j==m: bestp fallback, always ranked
        const unsigned p = (j < m) ? cp[urow*CAP + j] : bestp[urow];
        const float v = (float)(p >> 11) * (1.f/16384.f) - 64.f;
        if (j < m && v < thr2) continue;               // uniform within the 4-thread row group
        const int cidx = (int)(p & 2047u);
        const float4* cpn = (const float4*)(cbn + ((size_t)l*K_CB + cidx)*D_DIM + qo);
        double s = 0.0, n2 = 0.0;
        #pragma unroll
        for (int i = 0; i < 16; ++i) {
          const float4 a = cpn[i];
          s  = fma((double)r[i*4+0], (double)a.x, s);
          s  = fma((double)r[i*4+1], (double)a.y, s);
          s  = fma((double)r[i*4+2], (double)a.z, s);
          s  = fma((double)r[i*4+3], (double)a.w, s);
          n2 = fma((double)a.x, (double)a.x, n2);
          n2 = fma((double)a.y, (double)a.y, n2);
          n2 = fma((double)a.z, (double)a.z, n2);
          n2 = fma((double)a.w, (double)a.w, n2);
        }
        s  += __shfl_xor(s, 1, 64);  s  += __shfl_xor(s, 2, 64);
        n2 += __shfl_xor(n2, 1, 64); n2 += __shfl_xor(n2, 2, 64);
        const double sc = -2.0 * s + n2;
        if (sc < bsc || (sc == bsc && cidx < bidx)) { bsc = sc; bidx = cidx; }
      }
      bidx &= 2047;                                     // provably valid; belt-and-braces
      if (l == 0) id0 = bidx; else if (l == 1) id1 = bidx;
      else if (l == 2) id2 = bidx; else id3 = bidx;
      if ((t & 3) == 0) out_ids[(size_t)(row0 + urow)*L_NUM + l] = (float)bidx;

      // r -= raw q ; loss += ||r_new||^2
      const float4* qg = (const float4*)(cb + ((size_t)l*K_CB + bidx)*D_DIM + qo);
      #pragma unroll
      for (int i = 0; i < 16; ++i) {
        const float4 q = qg[i];
        r[i*4+0] -= q.x; r[i*4+1] -= q.y; r[i*4+2] -= q.z; r[i*4+3] -= q.w;
        lloss += (double)r[i*4+0]*r[i*4+0] + (double)r[i*4+1]*r[i*4+1]
               + (double)r[i*4+2]*r[i*4+2] + (double)r[i*4+3]*r[i*4+3];
      }
      if (l < 3) {                      // rebuild A16 for next layer
        #pragma unroll
        for (int j = 0; j < 8; ++j) {
          half8 h;
          #pragma unroll
          for (int e = 0; e < 8; ++e) h[e] = (_Float16)r[j*8+e];
          const int slot = (t & 3) * 8 + j;
          *(half8*)(A16 + slot*1024 + urow*8) = h;
        }
      }
    }
    __syncthreads();                    // tail reads of cp/gmax/bestp + A16 writes retired
    if (l < 3 && t < 128) { cn[t] = 0; gmax[t] = 0u; bestp[t] = 0u; }
    // next layer's stage0 + barrier separates these resets from first pushes
  }

  // ---- decoded = ((q0+q1)+q2)+q3 sequential fp32 (reference rounding) ----
  {
    float dec[64];
    #pragma unroll
    for (int l2 = 0; l2 < L_NUM; ++l2) {
      const int idl = (l2 == 0) ? id0 : (l2 == 1) ? id1 : (l2 == 2) ? id2 : id3;
      const float4* qg = (const float4*)(cb + ((size_t)l2*K_CB + idl)*D_DIM + qo);
      #pragma unroll
      for (int i = 0; i < 16; ++i) {
        const float4 q = qg[i];
        if (l2 == 0) { dec[i*4+0]=q.x; dec[i*4+1]=q.y; dec[i*4+2]=q.z; dec[i*4+3]=q.w; }
        else { dec[i*4+0]+=q.x; dec[i*4+1]+=q.y; dec[i*4+2]+=q.z; dec[i*4+3]+=q.w; }
      }
    }
    float4* dg = (float4*)(out_dec + (size_t)(row0 + urow)*D_DIM + qo);
    #pragma unroll
    for (int i = 0; i < 16; ++i)
      dg[i] = make_float4(dec[i*4+0], dec[i*4+1], dec[i*4+2], dec[i*4+3]);
  }

  // ---- loss reduction (lw overlays cp; all cp reads retired before last barrier) ----
  double* lw = (double*)cp;
  #pragma unroll
  for (int m = 1; m < 64; m <<= 1) lloss += __shfl_xor(lloss, m, 64);
  if (ln == 0) lw[wid] = lloss;
  __syncthreads();
  if (t == 0) {
    double s2 = 0.0;
    #pragma unroll
    for (int j = 0; j < 8; ++j) s2 += lw[j];
    atomicAdd(dloss, s2);
  }
}

__global__ void rq_fin_kernel(const double* __restrict__ dls, float* __restrict__ out_loss) {
  // loss = sum_l (1 + BETA) * ||r-q||^2 / n_elem  (codebook and commitment terms equal)
  out_loss[0] = (float)(dls[0] * 1.25 / 8388608.0);
}

extern "C" void kernel_launch(void* const* d_in, const int* in_sizes, int n_in,
                              void* d_out, int out_size, void* d_ws, size_t ws_size,
                              hipStream_t stream) {
  const float* x  = (const float*)d_in[0];
  const float* cb = (const float*)d_in[1];
  float* out      = (float*)d_out;
  float* out_ids  = out;                                   // [N][4] as float
  float* out_dec  = out + (size_t)N_ROWS * L_NUM;          // [N][256]
  float* out_loss = out_dec + (size_t)N_ROWS * D_DIM;

  char* w = (char*)d_ws;
  double* dls = (double*)w;                   w += 256;
  float* cbn = (float*)w;                     w += (size_t)L_NUM*K_CB*D_DIM*4;
  _Float16* cb16 = (_Float16*)w;              w += (size_t)L_NUM*K_CB*D_DIM*2;

  hipMemsetAsync(dls, 0, sizeof(double), stream);
  prep_all_kernel<<<L_NUM*K_CB, 64, 0, stream>>>(cb, cbn, cb16);

  const size_t smem = 65536 + 65536 + 128*CAP*4 + 512 + 512 + 512;   // 161280 B
  hipFuncSetAttribute(reinterpret_cast<const void*>(rq_fused_kernel),
                      hipFuncAttributeMaxDynamicSharedMemorySize, (int)smem);
  rq_fused_kernel<<<N_ROWS/128, 512, smem, stream>>>(x, cb, cbn, cb16,
                                                     out_ids, out_dec, dls);
  rq_fin_kernel<<<1, 1, 0, stream>>>(dls, out_loss);
}